// Round 9
// baseline (131.758 us; speedup 1.0000x reference)
//
#include <hip/hip_runtime.h>
#include <math.h>

// FC-CapsNet routing: u[128,1152,8], W[1152,32,8,16], b[1152,32] -> v[128,32,16]
// R9: R8 skeleton (no LDS tile, no barriers, direct-global W reads, L2-shared
// across same-XCD batch-groups) with: (1) inline W loads (no persistent w[]
// array) + __launch_bounds__(256,3) -> VGPR<=168, 3 waves/SIMD (R8 was 2);
// (2) STAGE-MAJOR softmax: the 8 per-batch shuffle chains advance in lockstep
// so each stage's 8 ds_swizzles issue back-to-back (throughput ~6cy each)
// instead of 8 serial latency chains; (3) u scalar-loads issued first.
// NOTE (profiling): dur_us includes fixed ~50us harness cost (256MiB d_ws
// 0xAA poison fill ~45us + d_in restore ~4us) as fillBufferAligned rows.

#define NB 128
#define NI 1152
#define NJ 32
#define DM 16
#define JMSZ 512            // NJ*DM
#define BB 8                // batches register-blocked per wave
#define TPB 256
#define BPB ((TPB / 64) * BB)  // 32 batches per block

template <int IC_, bool ATOMIC>
__global__ __launch_bounds__(TPB, 3) void caps_main(
    const float* __restrict__ u, const float* __restrict__ W,
    const float* __restrict__ bias, float* __restrict__ out, int nchunk) {
  const int chunk = blockIdx.x;
  const int bg = blockIdx.y;
  const int tid = threadIdx.x;
  const int wid = __builtin_amdgcn_readfirstlane(tid >> 6);
  const int lane = tid & 63;
  const int j = lane >> 1;                    // parent capsule 0..31
  const int h = lane & 1;                     // m-octet
  const int b0 = __builtin_amdgcn_readfirstlane(bg * BPB + wid * BB);
  const int i0 = chunk * IC_;

  float acc[BB][8];
#pragma unroll
  for (int bb = 0; bb < BB; ++bb)
#pragma unroll
    for (int k = 0; k < 8; ++k) acc[bb][k] = 0.f;

  // per-lane W base for this (j,h): byte offset j*512 + h*32 within a tile
  const char* wbase = (const char*)W + (size_t)i0 * 16384 + j * 512 + h * 32;

  for (int t = 0; t < IC_; ++t) {
    const int i = i0 + t;
    const char* wp = wbase + (size_t)t * 16384;

    // u scalar loads first (SGPR path, overlaps with vector W loads)
    float un[BB][8];
#pragma unroll
    for (int bb = 0; bb < BB; ++bb) {
      const float* up = u + ((size_t)(b0 + bb) * NI + i) * 8;
      float4 a0 = *(const float4*)up;
      float4 a1 = *(const float4*)(up + 4);
      un[bb][0] = a0.x; un[bb][1] = a0.y; un[bb][2] = a0.z; un[bb][3] = a0.w;
      un[bb][4] = a1.x; un[bb][5] = a1.y; un[bb][6] = a1.z; un[bb][7] = a1.w;
    }
    const float bj = bias[(size_t)i * NJ + j];

    float uh[BB][8];
#pragma unroll
    for (int bb = 0; bb < BB; ++bb)
#pragma unroll
      for (int k = 0; k < 8; ++k) uh[bb][k] = 0.f;

    // W loads inline per n (coalesced b128; compiler prefetches ahead
    // within the VGPR budget instead of pinning 64 regs for the tile)
#pragma unroll
    for (int n = 0; n < 8; ++n) {
      const float4 w0 = *(const float4*)(wp + n * 64);
      const float4 w1 = *(const float4*)(wp + n * 64 + 16);
#pragma unroll
      for (int bb = 0; bb < BB; ++bb) {
        const float uv = un[bb][n];
        uh[bb][0] = fmaf(uv, w0.x, uh[bb][0]);
        uh[bb][1] = fmaf(uv, w0.y, uh[bb][1]);
        uh[bb][2] = fmaf(uv, w0.z, uh[bb][2]);
        uh[bb][3] = fmaf(uv, w0.w, uh[bb][3]);
        uh[bb][4] = fmaf(uv, w1.x, uh[bb][4]);
        uh[bb][5] = fmaf(uv, w1.y, uh[bb][5]);
        uh[bb][6] = fmaf(uv, w1.z, uh[bb][6]);
        uh[bb][7] = fmaf(uv, w1.w, uh[bb][7]);
      }
    }

    // agreement + MAX-FREE softmax over j, STAGE-MAJOR across the 8 batches
    // so each stage's 8 independent ds_swizzles issue back-to-back.
    // lane = 2j+h: xor1 combines octets; xor2..32 sum e over the 32 j.
    float s2[BB], e[BB], es[BB];
#pragma unroll
    for (int bb = 0; bb < BB; ++bb) {
      float v = uh[bb][0] * uh[bb][0];
#pragma unroll
      for (int k = 1; k < 8; ++k) v = fmaf(uh[bb][k], uh[bb][k], v);
      s2[bb] = v;
    }
#pragma unroll
    for (int bb = 0; bb < BB; ++bb) s2[bb] += __shfl_xor(s2[bb], 1);
#pragma unroll
    for (int bb = 0; bb < BB; ++bb) e[bb] = __expf(s2[bb] * 0.25f);
#pragma unroll
    for (int bb = 0; bb < BB; ++bb) es[bb] = e[bb];
#pragma unroll
    for (int mask = 2; mask <= 32; mask <<= 1)
#pragma unroll
      for (int bb = 0; bb < BB; ++bb) es[bb] += __shfl_xor(es[bb], mask);
#pragma unroll
    for (int bb = 0; bb < BB; ++bb) {
      const float c = e[bb] * __builtin_amdgcn_rcpf(es[bb]) + bj;
#pragma unroll
      for (int k = 0; k < 8; ++k) acc[bb][k] = fmaf(c, uh[bb][k], acc[bb][k]);
    }
  }

#pragma unroll
  for (int bb = 0; bb < BB; ++bb) {
    if (ATOMIC) {
      float* p = out + (size_t)(b0 + bb) * JMSZ + j * DM + h * 8;
#pragma unroll
      for (int k = 0; k < 8; ++k) atomicAdd(p + k, acc[bb][k]);
    } else {
      float* p = out + ((size_t)(b0 + bb) * nchunk + chunk) * JMSZ + j * DM + h * 8;
      *(float4*)p = make_float4(acc[bb][0], acc[bb][1], acc[bb][2], acc[bb][3]);
      *(float4*)(p + 4) = make_float4(acc[bb][4], acc[bb][5], acc[bb][6], acc[bb][7]);
    }
  }
}

// Reduce chunk partials + squash, coalesced (proven R6-R8). Wave layout:
// q = lane>>3 (8 chunk-slices), r = lane&7 (8 consecutive float4s). Each
// thread sums NSUM/8 float4s at stride 2KB; q-combine via xor8/16/32;
// m-norm: 4 comps in-lane + xor1/xor2 over mq lanes.
template <int NSUM>
__global__ __launch_bounds__(256) void caps_fin(const float* __restrict__ part,
                                                float* __restrict__ v) {
  if constexpr (NSUM == 1) {
    const int o = blockIdx.x * 256 + threadIdx.x;   // b*512 + j*16 + m
    const float s = part[o];
    float sq = s * s;                               // m = lane bits 0..3
    sq += __shfl_xor(sq, 1);
    sq += __shfl_xor(sq, 2);
    sq += __shfl_xor(sq, 4);
    sq += __shfl_xor(sq, 8);
    const float nrm = sqrtf(sq);
    v[o] = (sq / (1.0f + sq)) / (nrm + 1e-20f) * s;
  } else {
    constexpr int QC = NSUM / 8;
    const int lane = threadIdx.x & 63;
    const int wv = (blockIdx.x * 256 + threadIdx.x) >> 6;  // global wave id
    const int q = lane >> 3;
    const int r = lane & 7;
    const int F = wv * 8 + r;                  // float4 id: b*128 + j*4 + mq
    const int b = F >> 7;
    const int jm4 = F & 127;
    const float* p = part + (size_t)b * NSUM * JMSZ + (size_t)q * QC * JMSZ + jm4 * 4;
    float4 s4 = make_float4(0.f, 0.f, 0.f, 0.f);
#pragma unroll 4
    for (int cc = 0; cc < QC; ++cc) {
      float4 x = *(const float4*)(p + (size_t)cc * JMSZ);
      s4.x += x.x; s4.y += x.y; s4.z += x.z; s4.w += x.w;
    }
#pragma unroll
    for (int mask = 8; mask <= 32; mask <<= 1) {   // combine 8 q-slices
      s4.x += __shfl_xor(s4.x, mask);
      s4.y += __shfl_xor(s4.y, mask);
      s4.z += __shfl_xor(s4.z, mask);
      s4.w += __shfl_xor(s4.w, mask);
    }
    float sq = s4.x * s4.x + s4.y * s4.y + s4.z * s4.z + s4.w * s4.w;
    sq += __shfl_xor(sq, 1);                   // mq bit0
    sq += __shfl_xor(sq, 2);                   // mq bit1
    const float nrm = sqrtf(sq);
    const float f = (sq / (1.0f + sq)) / (nrm + 1e-20f);
    if (q == 0)
      *(float4*)(v + (size_t)F * 4) = make_float4(f * s4.x, f * s4.y, f * s4.z, f * s4.w);
  }
}

extern "C" void kernel_launch(void* const* d_in, const int* in_sizes, int n_in,
                              void* d_out, int out_size, void* d_ws, size_t ws_size,
                              hipStream_t stream) {
  const float* u = (const float*)d_in[0];
  const float* W = (const float*)d_in[1];
  const float* bias = (const float*)d_in[2];
  float* out = (float*)d_out;

  const size_t P128 = (size_t)NB * 128 * JMSZ * sizeof(float);  // 32 MB
  const size_t P64 = (size_t)NB * 64 * JMSZ * sizeof(float);    // 16 MB

  if (ws_size >= P128) {
    // grid (128,4)=512 blocks of 256 thr, no LDS -> 12 waves/CU (VGPR<=168).
    // 128%8==0: all 4 bg of a chunk share an XCD -> W L2-resident (2.3MB/XCD).
    float* part = (float*)d_ws;
    caps_main<9, false><<<dim3(128, NB / BPB), TPB, 0, stream>>>(u, W, bias, part, 128);
    caps_fin<128><<<512, 256, 0, stream>>>(part, out);
  } else if (ws_size >= P64) {
    float* part = (float*)d_ws;
    caps_main<18, false><<<dim3(64, NB / BPB), TPB, 0, stream>>>(u, W, bias, part, 64);
    caps_fin<64><<<512, 256, 0, stream>>>(part, out);
  } else {
    float* sbuf = (float*)d_ws;
    hipMemsetAsync(sbuf, 0, (size_t)NB * JMSZ * sizeof(float), stream);
    caps_main<18, true><<<dim3(64, NB / BPB), TPB, 0, stream>>>(u, W, bias, sbuf, 64);
    caps_fin<1><<<(NB * JMSZ) / 256, 256, 0, stream>>>(sbuf, out);
  }
}

// Round 10
// 111.657 us; speedup vs baseline: 1.1800x; 1.1800x over previous
//
#include <hip/hip_runtime.h>
#include <math.h>

// FC-CapsNet routing: u[128,1152,8], W[1152,32,8,16], b[1152,32] -> v[128,32,16]
// R10: R8 skeleton (no LDS tile, no barriers, direct-global W, partials<=32MB)
// with the occupancy actually doubled: BB=4 -> 4096 waves total, grid
// (128,8)=1024 blocks = 4 blocks/CU = 4 waves/SIMD (R8/R9 were grid-limited
// to 2/SIMD). W loads in TWO up-front batches of 8 b128 (n=0..3 then 4..7):
// early issue (R8's win, R9's regression when inlined) at ~16 regs instead
// of 64. launch_bounds(256,4) caps VGPR at 128 to keep 4 blocks/CU.
// NOTE (profiling): dur_us includes fixed ~50us harness cost (256MiB d_ws
// 0xAA poison fill ~45us + d_in restore ~4us) as fillBufferAligned rows.

#define NB 128
#define NI 1152
#define NJ 32
#define DM 16
#define JMSZ 512            // NJ*DM
#define BB 4                // batches register-blocked per wave
#define TPB 256
#define BPB ((TPB / 64) * BB)  // 16 batches per block

template <int IC_, bool ATOMIC>
__global__ __launch_bounds__(TPB, 4) void caps_main(
    const float* __restrict__ u, const float* __restrict__ W,
    const float* __restrict__ bias, float* __restrict__ out, int nchunk) {
  const int chunk = blockIdx.x;
  const int bg = blockIdx.y;
  const int tid = threadIdx.x;
  const int wid = __builtin_amdgcn_readfirstlane(tid >> 6);
  const int lane = tid & 63;
  const int j = lane >> 1;                    // parent capsule 0..31
  const int h = lane & 1;                     // m-octet
  const int b0 = __builtin_amdgcn_readfirstlane(bg * BPB + wid * BB);
  const int i0 = chunk * IC_;

  float acc[BB][8];
#pragma unroll
  for (int bb = 0; bb < BB; ++bb)
#pragma unroll
    for (int k = 0; k < 8; ++k) acc[bb][k] = 0.f;

  // per-lane W base for this (j,h): byte offset j*512 + h*32 within a tile
  const char* wbase = (const char*)W + (size_t)i0 * 16384 + j * 512 + h * 32;

  for (int t = 0; t < IC_; ++t) {
    const int i = i0 + t;
    const char* wp = wbase + (size_t)t * 16384;

    // u scalar loads (wave-uniform addresses -> SGPR path)
    float un[BB][8];
#pragma unroll
    for (int bb = 0; bb < BB; ++bb) {
      const float* up = u + ((size_t)(b0 + bb) * NI + i) * 8;
      float4 a0 = *(const float4*)up;
      float4 a1 = *(const float4*)(up + 4);
      un[bb][0] = a0.x; un[bb][1] = a0.y; un[bb][2] = a0.z; un[bb][3] = a0.w;
      un[bb][4] = a1.x; un[bb][5] = a1.y; un[bb][6] = a1.z; un[bb][7] = a1.w;
    }
    const float bj = bias[(size_t)i * NJ + j];

    float uh[BB][8];
#pragma unroll
    for (int bb = 0; bb < BB; ++bb)
#pragma unroll
      for (int k = 0; k < 8; ++k) uh[bb][k] = 0.f;

    // W loads in two up-front batches (early issue, bounded registers)
#pragma unroll
    for (int half = 0; half < 2; ++half) {
      float4 w0[4], w1[4];
#pragma unroll
      for (int nn = 0; nn < 4; ++nn) {
        const int n = half * 4 + nn;
        w0[nn] = *(const float4*)(wp + n * 64);
        w1[nn] = *(const float4*)(wp + n * 64 + 16);
      }
#pragma unroll
      for (int nn = 0; nn < 4; ++nn) {
        const int n = half * 4 + nn;
#pragma unroll
        for (int bb = 0; bb < BB; ++bb) {
          const float uv = un[bb][n];
          uh[bb][0] = fmaf(uv, w0[nn].x, uh[bb][0]);
          uh[bb][1] = fmaf(uv, w0[nn].y, uh[bb][1]);
          uh[bb][2] = fmaf(uv, w0[nn].z, uh[bb][2]);
          uh[bb][3] = fmaf(uv, w0[nn].w, uh[bb][3]);
          uh[bb][4] = fmaf(uv, w1[nn].x, uh[bb][4]);
          uh[bb][5] = fmaf(uv, w1[nn].y, uh[bb][5]);
          uh[bb][6] = fmaf(uv, w1[nn].z, uh[bb][6]);
          uh[bb][7] = fmaf(uv, w1[nn].w, uh[bb][7]);
        }
      }
    }

    // agreement + MAX-FREE softmax over j, STAGE-MAJOR across batches
    // (independent shuffle chains issue back-to-back).
    // lane = 2j+h: xor1 combines octets; xor2..32 sum e over the 32 j.
    float s2[BB], e[BB], es[BB];
#pragma unroll
    for (int bb = 0; bb < BB; ++bb) {
      float v = uh[bb][0] * uh[bb][0];
#pragma unroll
      for (int k = 1; k < 8; ++k) v = fmaf(uh[bb][k], uh[bb][k], v);
      s2[bb] = v;
    }
#pragma unroll
    for (int bb = 0; bb < BB; ++bb) s2[bb] += __shfl_xor(s2[bb], 1);
#pragma unroll
    for (int bb = 0; bb < BB; ++bb) e[bb] = __expf(s2[bb] * 0.25f);
#pragma unroll
    for (int bb = 0; bb < BB; ++bb) es[bb] = e[bb];
#pragma unroll
    for (int mask = 2; mask <= 32; mask <<= 1)
#pragma unroll
      for (int bb = 0; bb < BB; ++bb) es[bb] += __shfl_xor(es[bb], mask);
#pragma unroll
    for (int bb = 0; bb < BB; ++bb) {
      const float c = e[bb] * __builtin_amdgcn_rcpf(es[bb]) + bj;
#pragma unroll
      for (int k = 0; k < 8; ++k) acc[bb][k] = fmaf(c, uh[bb][k], acc[bb][k]);
    }
  }

#pragma unroll
  for (int bb = 0; bb < BB; ++bb) {
    if (ATOMIC) {
      float* p = out + (size_t)(b0 + bb) * JMSZ + j * DM + h * 8;
#pragma unroll
      for (int k = 0; k < 8; ++k) atomicAdd(p + k, acc[bb][k]);
    } else {
      float* p = out + ((size_t)(b0 + bb) * nchunk + chunk) * JMSZ + j * DM + h * 8;
      *(float4*)p = make_float4(acc[bb][0], acc[bb][1], acc[bb][2], acc[bb][3]);
      *(float4*)(p + 4) = make_float4(acc[bb][4], acc[bb][5], acc[bb][6], acc[bb][7]);
    }
  }
}

// Reduce chunk partials + squash, coalesced (proven R6-R9). Wave layout:
// q = lane>>3 (8 chunk-slices), r = lane&7 (8 consecutive float4s). Each
// thread sums NSUM/8 float4s at stride 2KB; q-combine via xor8/16/32;
// m-norm: 4 comps in-lane + xor1/xor2 over mq lanes.
template <int NSUM>
__global__ __launch_bounds__(256) void caps_fin(const float* __restrict__ part,
                                                float* __restrict__ v) {
  if constexpr (NSUM == 1) {
    const int o = blockIdx.x * 256 + threadIdx.x;   // b*512 + j*16 + m
    const float s = part[o];
    float sq = s * s;                               // m = lane bits 0..3
    sq += __shfl_xor(sq, 1);
    sq += __shfl_xor(sq, 2);
    sq += __shfl_xor(sq, 4);
    sq += __shfl_xor(sq, 8);
    const float nrm = sqrtf(sq);
    v[o] = (sq / (1.0f + sq)) / (nrm + 1e-20f) * s;
  } else {
    constexpr int QC = NSUM / 8;
    const int lane = threadIdx.x & 63;
    const int wv = (blockIdx.x * 256 + threadIdx.x) >> 6;  // global wave id
    const int q = lane >> 3;
    const int r = lane & 7;
    const int F = wv * 8 + r;                  // float4 id: b*128 + j*4 + mq
    const int b = F >> 7;
    const int jm4 = F & 127;
    const float* p = part + (size_t)b * NSUM * JMSZ + (size_t)q * QC * JMSZ + jm4 * 4;
    float4 s4 = make_float4(0.f, 0.f, 0.f, 0.f);
#pragma unroll 4
    for (int cc = 0; cc < QC; ++cc) {
      float4 x = *(const float4*)(p + (size_t)cc * JMSZ);
      s4.x += x.x; s4.y += x.y; s4.z += x.z; s4.w += x.w;
    }
#pragma unroll
    for (int mask = 8; mask <= 32; mask <<= 1) {   // combine 8 q-slices
      s4.x += __shfl_xor(s4.x, mask);
      s4.y += __shfl_xor(s4.y, mask);
      s4.z += __shfl_xor(s4.z, mask);
      s4.w += __shfl_xor(s4.w, mask);
    }
    float sq = s4.x * s4.x + s4.y * s4.y + s4.z * s4.z + s4.w * s4.w;
    sq += __shfl_xor(sq, 1);                   // mq bit0
    sq += __shfl_xor(sq, 2);                   // mq bit1
    const float nrm = sqrtf(sq);
    const float f = (sq / (1.0f + sq)) / (nrm + 1e-20f);
    if (q == 0)
      *(float4*)(v + (size_t)F * 4) = make_float4(f * s4.x, f * s4.y, f * s4.z, f * s4.w);
  }
}

extern "C" void kernel_launch(void* const* d_in, const int* in_sizes, int n_in,
                              void* d_out, int out_size, void* d_ws, size_t ws_size,
                              hipStream_t stream) {
  const float* u = (const float*)d_in[0];
  const float* W = (const float*)d_in[1];
  const float* bias = (const float*)d_in[2];
  float* out = (float*)d_out;

  const size_t P128 = (size_t)NB * 128 * JMSZ * sizeof(float);  // 32 MB
  const size_t P64 = (size_t)NB * 64 * JMSZ * sizeof(float);    // 16 MB

  if (ws_size >= P128) {
    // grid (128,8)=1024 blocks of 256 thr, no LDS, VGPR<=128
    // -> 4 blocks/CU = 16 waves/CU = 4 waves/SIMD.
    float* part = (float*)d_ws;
    caps_main<9, false><<<dim3(128, NB / BPB), TPB, 0, stream>>>(u, W, bias, part, 128);
    caps_fin<128><<<512, 256, 0, stream>>>(part, out);
  } else if (ws_size >= P64) {
    float* part = (float*)d_ws;
    caps_main<18, false><<<dim3(64, NB / BPB), TPB, 0, stream>>>(u, W, bias, part, 64);
    caps_fin<64><<<512, 256, 0, stream>>>(part, out);
  } else {
    float* sbuf = (float*)d_ws;
    hipMemsetAsync(sbuf, 0, (size_t)NB * JMSZ * sizeof(float), stream);
    caps_main<18, true><<<dim3(64, NB / BPB), TPB, 0, stream>>>(u, W, bias, sbuf, 64);
    caps_fin<1><<<(NB * JMSZ) / 256, 256, 0, stream>>>(sbuf, out);
  }
}